// Round 2
// 410.372 us; speedup vs baseline: 1.1364x; 1.1364x over previous
//
#include <hip/hip_runtime.h>
#include <stdint.h>

// Shapes: B=32, N=1024, F=512, G=16, S=64, D=256, conv window 32, Cout=512, Tout=993.
// I/O is fp32 (per reference); internal compute bf16 MFMA.
// ROUND 9: byte-identical to the known-PASS round-2 kernel EXCEPT k_conv_gemm's grid
// dimension ORDER (batch fastest, o-tile slowest) so the 8 XCDs keep one 2MB cwT
// o-tile L2-resident each -> predicted FETCH_SIZE 990MB -> ~150-350MB. No sync/LDS/
// staging changes (R8's 8-phase rewrite died at container level x2, same signature
// as prior session's R4-R6 restructures; this round doubles as the infra bisect).

typedef __bf16  bf16x8 __attribute__((ext_vector_type(8)));
typedef float   f32x4  __attribute__((ext_vector_type(4)));

__device__ __forceinline__ uint16_t f2bf(float f) {
    union { float f; uint32_t u; } x; x.f = f;
    uint32_t r = x.u + 0x7FFFu + ((x.u >> 16) & 1u);   // RTNE
    return (uint16_t)(r >> 16);
}
__device__ __forceinline__ float bf2f(uint16_t h) {
    union { uint32_t u; float f; } x; x.u = ((uint32_t)h) << 16; return x.f;
}
// async global->LDS, 16B per lane. LDS dest = wave-uniform base + lane*16 (HW rule).
template <typename T>
__device__ __forceinline__ void gl2lds16(const T* g, T* l) {
    __builtin_amdgcn_global_load_lds(
        (const __attribute__((address_space(1))) uint32_t*)g,
        (__attribute__((address_space(3))) uint32_t*)l, 16, 0, 0);
}

// ---------------- fp32 -> bf16 tiled transpose: in (R,C) f32 -> out (C,R) bf16, z = matrix
__global__ void transpose_cvt(const float* __restrict__ in, uint16_t* __restrict__ out,
                              int R, int C) {
    __shared__ float tile[32][33];
    const float* inm = in + (size_t)blockIdx.z * R * C;
    uint16_t* outm = out + (size_t)blockIdx.z * R * C;
    int c0 = blockIdx.x * 32, r0 = blockIdx.y * 32;
    int tx = threadIdx.x, ty = threadIdx.y;            // (32, 8)
    #pragma unroll
    for (int i = 0; i < 32; i += 8)
        tile[ty + i][tx] = inm[(size_t)(r0 + ty + i) * C + (c0 + tx)];
    __syncthreads();
    #pragma unroll
    for (int i = 0; i < 32; i += 8)
        outm[(size_t)(c0 + ty + i) * R + (r0 + tx)] = f2bf(tile[tx][ty + i]);
}

// ---------------- Kernel 1: gathered grouped GEMM -> intermediate (32*1024+64, 256) bf16
// A: x fp32 gathered rows, staged fp32 in LDS, cvt->bf16 at fragment read.
// grid: (x=2 d-tiles, y=16 batch-pairs, z=16 groups), 256 threads (4 waves, 2x2 wave grid)
__global__ __launch_bounds__(256, 2)
void k_group_gemm(const float*    __restrict__ x,    // (32,1024,512) f32
                  const int*      __restrict__ idx,  // (16,64)
                  const uint16_t* __restrict__ Wt,   // (16,256,512) bf16 (W^T per group)
                  const float*    __restrict__ bias, // (16,256) f32
                  uint16_t*       __restrict__ interm) {
    __shared__ float    smemA[128 * 64];              // 32 KB, 16-slot xor swizzle
    __shared__ uint16_t smemB[128 * 64];              // 16 KB, 8-slot xor swizzle
    __shared__ int sidx[64];
    const int tid  = threadIdx.x;
    const int g    = blockIdx.z;
    const int bp   = blockIdx.y;                      // batches 2bp, 2bp+1
    const int n0   = blockIdx.x * 128;                // d tile base
    const int wave = tid >> 6, lane = tid & 63;
    const int quad = lane >> 4, l15 = lane & 15;
    const int mw = (wave & 1) * 64, nw = (wave >> 1) * 64;

    if (tid < 64) sidx[tid] = idx[g * 64 + tid];
    __syncthreads();

    // ---- A staging map (fp32): per issue 4 rows; lane -> row lane>>4, slot lane&15
    uint32_t aoffF[8];
    #pragma unroll
    for (int is = 0; is < 8; ++is) {
        int r = wave * 32 + is * 4 + (lane >> 4);     // tile row 0..127
        int b = bp * 2 + (r >> 6), s = r & 63;
        int gc = (lane & 15) ^ (r & 15);              // xor-swizzled 4-float chunk
        aoffF[is] = ((uint32_t)b * 1024u + (uint32_t)sidx[s]) * 512u + (uint32_t)gc * 4u;
    }
    // ---- B staging map (bf16): per issue 8 rows; lane -> row lane>>3, slot lane&7
    uint32_t boff[4];
    #pragma unroll
    for (int is = 0; is < 4; ++is) {
        int r = wave * 32 + is * 8 + (lane >> 3);
        int gc8 = ((lane & 7) ^ (lane >> 3)) * 8;
        boff[is] = ((uint32_t)(g * 256 + n0 + r)) * 512u + (uint32_t)gc8;
    }

    f32x4 acc[4][4];
    #pragma unroll
    for (int i = 0; i < 4; ++i)
        #pragma unroll
        for (int j = 0; j < 4; ++j)
            #pragma unroll
            for (int c = 0; c < 4; ++c) acc[i][j][c] = 0.f;

    for (int kb = 0; kb < 8; ++kb) {                  // K = 512, BK = 64
        #pragma unroll
        for (int is = 0; is < 8; ++is)
            gl2lds16(x + aoffF[is] + kb * 64, &smemA[(wave * 32 + is * 4) * 64]);
        #pragma unroll
        for (int is = 0; is < 4; ++is)
            gl2lds16(Wt + boff[is] + kb * 64, &smemB[(wave * 32 + is * 8) * 64]);
        __syncthreads();
        #pragma unroll
        for (int ks = 0; ks < 2; ++ks) {
            const int kc = ks * 4 + quad;             // 8-elem k-chunk index 0..7
            bf16x8 af[4], bfr[4];
            #pragma unroll
            for (int i = 0; i < 4; ++i) {
                int m = mw + i * 16 + l15;
                int s0 = (2 * kc) ^ (m & 15);
                int s1 = (2 * kc + 1) ^ (m & 15);
                f32x4 f0 = *(const f32x4*)&smemA[m * 64 + s0 * 4];
                f32x4 f1 = *(const f32x4*)&smemA[m * 64 + s1 * 4];
                #pragma unroll
                for (int j = 0; j < 4; ++j) { af[i][j] = (__bf16)f0[j]; af[i][j + 4] = (__bf16)f1[j]; }
            }
            #pragma unroll
            for (int j = 0; j < 4; ++j) {
                int n = nw + j * 16 + l15;
                bfr[j] = *(const bf16x8*)&smemB[(n * 8 + (kc ^ (n & 7))) * 8];
            }
            #pragma unroll
            for (int i = 0; i < 4; ++i)
                #pragma unroll
                for (int j = 0; j < 4; ++j)
                    acc[i][j] = __builtin_amdgcn_mfma_f32_16x16x32_bf16(af[i], bfr[j], acc[i][j], 0, 0, 0);
        }
        __syncthreads();
    }

    // epilogue: +bias(f32), store bf16 into interm rows (b*1024 + g*64 + s)
    #pragma unroll
    for (int j = 0; j < 4; ++j) {
        int col = n0 + nw + j * 16 + l15;
        float bv = bias[g * 256 + col];
        #pragma unroll
        for (int i = 0; i < 4; ++i) {
            int mbase = mw + i * 16 + quad * 4;
            #pragma unroll
            for (int r = 0; r < 4; ++r) {
                int m = mbase + r;
                int b = bp * 2 + (m >> 6), s = m & 63;
                interm[((size_t)b * 1024 + g * 64 + s) * 256 + col] = f2bf(acc[i][j][r] + bv);
            }
        }
    }
}

// ---------------- Kernel 2: conv as GEMM. M=993(per batch, tiled 128), N=512, K=8192
// grid: (x=32 batches, y=8 t-tiles, z=4 o-tiles) -- batch FASTEST so consecutive
// blocks (round-robin across 8 XCDs) share the same 2MB cwT o-tile; each XCD keeps
// its o-tile L2-resident for a whole 256-block chunk -> B re-fetch ~900MB -> ~64MB.
__global__ __launch_bounds__(256, 2)
void k_conv_gemm(const uint16_t* __restrict__ interm, // (32*1024+64, 256) bf16
                 const uint16_t* __restrict__ cwT,    // (512, 8192) bf16: [o][k*256+c]
                 const float*    __restrict__ cb,     // (512) f32
                 float*          __restrict__ y) {    // (32, 993, 512) f32
    __shared__ uint16_t smem[16384];                  // A:[0,8192) B:[8192,16384)
    const int tid  = threadIdx.x;
    const int n0   = blockIdx.z * 128;                // out-channel tile (slowest)
    const int t0   = blockIdx.y * 128;                // time tile
    const int nb   = blockIdx.x;                      // batch (fastest)
    const int wave = tid >> 6, lane = tid & 63;
    const int quad = lane >> 4, l15 = lane & 15;
    const int mw = (wave & 1) * 64, nw = (wave >> 1) * 64;

    const int srow = wave * 32 + (lane >> 3);
    const int gc8  = ((lane & 7) ^ (lane >> 3)) * 8;

    uint32_t aoff[4], boff[4];
    #pragma unroll
    for (int is = 0; is < 4; ++is) {
        int r = srow + is * 8;
        aoff[is] = ((uint32_t)(nb * 1024 + t0 + r)) * 256u + gc8;
        boff[is] = ((uint32_t)(n0 + r)) * 8192u + gc8;
    }

    f32x4 acc[4][4];
    #pragma unroll
    for (int i = 0; i < 4; ++i)
        #pragma unroll
        for (int j = 0; j < 4; ++j)
            #pragma unroll
            for (int c = 0; c < 4; ++c) acc[i][j][c] = 0.f;

    for (int kb = 0; kb < 128; ++kb) {                // K = 8192, BK = 64
        const int k  = kb >> 2;                       // conv tap 0..31
        const int c0 = (kb & 3) * 64;                 // channel block
        #pragma unroll
        for (int is = 0; is < 4; ++is) {
            gl2lds16(interm + aoff[is] + (uint32_t)k * 256u + c0,
                     &smem[(wave * 32 + is * 8) * 64]);
            gl2lds16(cwT + boff[is] + (uint32_t)kb * 64u,
                     &smem[8192 + (wave * 32 + is * 8) * 64]);
        }
        __syncthreads();
        #pragma unroll
        for (int ks = 0; ks < 2; ++ks) {
            const int kc = ks * 4 + quad;
            bf16x8 af[4], bfr[4];
            #pragma unroll
            for (int i = 0; i < 4; ++i) {
                int m = mw + i * 16 + l15;
                af[i] = *(const bf16x8*)&smem[(m * 8 + (kc ^ (m & 7))) * 8];
            }
            #pragma unroll
            for (int j = 0; j < 4; ++j) {
                int n = nw + j * 16 + l15;
                bfr[j] = *(const bf16x8*)&smem[8192 + (n * 8 + (kc ^ (n & 7))) * 8];
            }
            #pragma unroll
            for (int i = 0; i < 4; ++i)
                #pragma unroll
                for (int j = 0; j < 4; ++j)
                    acc[i][j] = __builtin_amdgcn_mfma_f32_16x16x32_bf16(af[i], bfr[j], acc[i][j], 0, 0, 0);
        }
        __syncthreads();
    }

    // epilogue: +conv_b(f32), leaky relu, store f32, valid t < 993
    #pragma unroll
    for (int j = 0; j < 4; ++j) {
        int col = n0 + nw + j * 16 + l15;
        float bv = cb[col];
        #pragma unroll
        for (int i = 0; i < 4; ++i) {
            int tb = t0 + mw + i * 16 + quad * 4;
            #pragma unroll
            for (int r = 0; r < 4; ++r) {
                int t = tb + r;
                if (t < 993) {
                    float v = acc[i][j][r] + bv;
                    v = (v >= 0.f) ? v : 0.2f * v;
                    y[((size_t)nb * 993 + t) * 512 + col] = v;
                }
            }
        }
    }
}

extern "C" void kernel_launch(void* const* d_in, const int* in_sizes, int n_in,
                              void* d_out, int out_size, void* d_ws, size_t ws_size,
                              hipStream_t stream) {
    const float* x   = (const float*)d_in[0];   // (32,1024,512) f32
    const int*   idx = (const int*)  d_in[1];   // (16,64) i32
    const float* W   = (const float*)d_in[2];   // (16,512,256) f32
    const float* b   = (const float*)d_in[3];   // (16,256) f32
    const float* cw  = (const float*)d_in[4];   // (32,256,512) f32
    const float* cb  = (const float*)d_in[5];   // (512) f32
    float* out = (float*)d_out;                 // (32,993,512) f32

    // workspace (bf16 elems): interm (32832,256) | Wt (16,256,512) | cwT (512,8192)  ~29.4 MB
    uint16_t* interm = (uint16_t*)d_ws;
    uint16_t* Wt  = interm + (size_t)32832 * 256;
    uint16_t* cwT = Wt + (size_t)16 * 256 * 512;

    // W (g,512,256) f32 -> Wt (g,256,512) bf16
    transpose_cvt<<<dim3(256 / 32, 512 / 32, 16), dim3(32, 8), 0, stream>>>(W, Wt, 512, 256);
    // conv_w (8192,512) f32 -> cwT (512,8192) bf16
    transpose_cvt<<<dim3(512 / 32, 8192 / 32, 1), dim3(32, 8), 0, stream>>>(cw, cwT, 8192, 512);

    k_group_gemm<<<dim3(2, 16, 16), 256, 0, stream>>>(x, idx, Wt, b, interm);
    k_conv_gemm <<<dim3(32, 8, 4),  256, 0, stream>>>(interm, cwT, cb, out);
}